// Round 1
// baseline (127.796 us; speedup 1.0000x reference)
//
#include <hip/hip_runtime.h>
#include <math.h>

// VoltageNet: per-batch (512) chained scans over T=8192.
//   UH == 0 identically (theta[3]=theta[4]=0 since LB==UB==0) -> 1-state affine recurrence.
//   Block-per-batch: phase1 load+Tmean, phase2a SOC prefix scan, phase2b MLP+OCV+affine
//   coefficients (theta computed ONCE per element), affine block scan, phase3 output.
// LDS padded j+(j>>5): thread-owned stride-32 walk -> consecutive banks (2-way max, free).

#define TT   8192
#define BLK  256
#define EPT  32
#define PADJ(j) ((j) + ((j) >> 5))

__device__ __forceinline__ float frcp(float x)  { return __builtin_amdgcn_rcpf(x); }
__device__ __forceinline__ float fsigm(float z) { return frcp(1.0f + __expf(-z)); }
__device__ __forceinline__ float ftanh(float z) { return 1.0f - 2.0f * frcp(__expf(2.0f * z) + 1.0f); }
__device__ __forceinline__ float fsoftplus(float z) {
    return fmaxf(z, 0.0f) + __logf(1.0f + __expf(-fabsf(z)));
}

__global__ void __launch_bounds__(BLK, 2)
voltnet_kernel(const float* __restrict__ X, const float* __restrict__ SC,
               const float* __restrict__ W1, const float* __restrict__ b1,
               const float* __restrict__ W2, const float* __restrict__ b2,
               float* __restrict__ out)
{
    __shared__ float ldsA[PADJ(TT - 1) + 2];   // t -> local dSOC prefix -> stash P
    __shared__ float ldsB[PADJ(TT - 1) + 2];   // I -> stash Apre
    __shared__ float wred[4];
    __shared__ float sA[4], sB[4];
    __shared__ float U1arr[BLK];
    __shared__ float bcU10;

    const int b    = blockIdx.x;
    const int tid  = threadIdx.x;
    const int lane = tid & 63;
    const int wv   = tid >> 6;
    const int s    = tid * EPT;

    const float* __restrict__ Xrow = X + (size_t)b * TT * 3;
    const float Q  = SC[2 * b + 0];
    const float R0 = SC[2 * b + 1];

    // weights -> uniform loads (SGPRs)
    float w1[18], bb1[6], w2[42], bb2[7];
    #pragma unroll
    for (int i = 0; i < 18; ++i) w1[i] = W1[i];
    #pragma unroll
    for (int i = 0; i < 6;  ++i) bb1[i] = b1[i];
    #pragma unroll
    for (int i = 0; i < 42; ++i) w2[i] = W2[i];
    #pragma unroll
    for (int i = 0; i < 7;  ++i) bb2[i] = b2[i];

    // ---- Phase 1: coalesced load of (t, I) into LDS; accumulate Temp sum ----
    float tsum = 0.0f;
    #pragma unroll 4
    for (int it = 0; it < EPT; ++it) {
        int j = tid + it * BLK;
        float tt = Xrow[3 * j + 0];
        float ii = Xrow[3 * j + 1];
        float tp = Xrow[3 * j + 2];
        ldsA[PADJ(j)] = tt;
        ldsB[PADJ(j)] = ii;
        tsum += tp;
    }
    #pragma unroll
    for (int d = 32; d > 0; d >>= 1) tsum += __shfl_down(tsum, d, 64);
    if (lane == 0) wred[wv] = tsum;
    __syncthreads();                                    // S1
    const float Tmean = (wred[0] + wred[1] + wred[2] + wred[3]) * (1.0f / (float)TT);

    // per-batch constant part of layer-1 pre-activation
    float pre1[6];
    #pragma unroll
    for (int o = 0; o < 6; ++o) pre1[o] = fmaf(R0, w1[6 + o], fmaf(Tmean, w1[12 + o], bb1[o]));

    // ---- Phase 2a: local dSOC prefix (in-place into ldsA) ----
    float tprev = 0.0f, iprev = 0.0f;
    if (tid > 0) { tprev = ldsA[PADJ(s - 1)]; iprev = ldsB[PADJ(s - 1)]; }
    __syncthreads();                                    // S2 (protect boundary reads)
    float lp = 0.0f;
    #pragma unroll 4
    for (int e = 0; e < EPT; ++e) {
        int j = s + e;
        float tt = ldsA[PADJ(j)];
        float ii = ldsB[PADJ(j)];
        float ds = (ii + iprev) * (tt - tprev) * (1.0f / 36000.0f);
        if (j == 0) ds = 0.0f;
        lp += ds;
        ldsA[PADJ(j)] = lp;     // inclusive local prefix
        tprev = tt; iprev = ii;
    }
    // block exclusive scan of thread totals
    float inc = lp;
    #pragma unroll
    for (int d = 1; d < 64; d <<= 1) {
        float v = __shfl_up(inc, d, 64);
        if (lane >= d) inc += v;
    }
    if (lane == 63) wred[wv] = inc;
    __syncthreads();                                    // S3
    float woff = 0.0f;
    for (int w = 0; w < wv; ++w) woff += wred[w];
    const float soc_base = fmaf(Q, 0.2f, woff + (inc - lp));   // Q/QN + exclusive prefix

    // boundary I for the thread's last step (thread 255: step T-1 doesn't exist)
    float inext_last = (tid < BLK - 1) ? ldsB[PADJ(s + EPT)] : 0.0f;
    __syncthreads();                                    // S4

    // ---- Phase 2b: theta + OCV + affine coefficients; stash (P, Apre) in LDS ----
    float Ap = 1.0f, Bp = 0.0f;
    float U10_local = 0.0f;
    #pragma unroll 2
    for (int e = 0; e < EPT; ++e) {
        int j = s + e;
        float soc = soc_base + ldsA[PADJ(j)];
        float ii  = ldsB[PADJ(j)];
        float inx = (e == EPT - 1) ? inext_last : ldsB[PADJ(j + 1)];

        // MLP layer 1 (softplus)
        float h0 = fsoftplus(fmaf(soc, w1[0], pre1[0]));
        float h1 = fsoftplus(fmaf(soc, w1[1], pre1[1]));
        float h2 = fsoftplus(fmaf(soc, w1[2], pre1[2]));
        float h3 = fsoftplus(fmaf(soc, w1[3], pre1[3]));
        float h4 = fsoftplus(fmaf(soc, w1[4], pre1[4]));
        float h5 = fsoftplus(fmaf(soc, w1[5], pre1[5]));

        // MLP layer 2 — only outputs 0,1,5,6 needed (2 only at j==0)
        float p0 = bb2[0], p1 = bb2[1], p5 = bb2[5], p6 = bb2[6];
        p0 = fmaf(h0, w2[0*7+0], p0); p1 = fmaf(h0, w2[0*7+1], p1);
        p5 = fmaf(h0, w2[0*7+5], p5); p6 = fmaf(h0, w2[0*7+6], p6);
        p0 = fmaf(h1, w2[1*7+0], p0); p1 = fmaf(h1, w2[1*7+1], p1);
        p5 = fmaf(h1, w2[1*7+5], p5); p6 = fmaf(h1, w2[1*7+6], p6);
        p0 = fmaf(h2, w2[2*7+0], p0); p1 = fmaf(h2, w2[2*7+1], p1);
        p5 = fmaf(h2, w2[2*7+5], p5); p6 = fmaf(h2, w2[2*7+6], p6);
        p0 = fmaf(h3, w2[3*7+0], p0); p1 = fmaf(h3, w2[3*7+1], p1);
        p5 = fmaf(h3, w2[3*7+5], p5); p6 = fmaf(h3, w2[3*7+6], p6);
        p0 = fmaf(h4, w2[4*7+0], p0); p1 = fmaf(h4, w2[4*7+1], p1);
        p5 = fmaf(h4, w2[4*7+5], p5); p6 = fmaf(h4, w2[4*7+6], p6);
        p0 = fmaf(h5, w2[5*7+0], p0); p1 = fmaf(h5, w2[5*7+1], p1);
        p5 = fmaf(h5, w2[5*7+5], p5); p6 = fmaf(h5, w2[5*7+6], p6);

        float R1 = 0.04f   * fsigm(0.01f * p0);
        float C  = 1e-6f   * fsigm(0.01f * p1);
        float ox = fmaf(0.79764f, fsigm(0.01f * p5), 0.04236f);
        float oy = fmaf(0.82504f, fsigm(0.01f * p6), 0.023f);

        // OCV curve
        float up = fmaf(oy, fmaf(oy, fmaf(oy, fmaf(oy, fmaf(oy, -2.2166f, 3.5146f),
                        -2.0843f), 1.6225f), -1.6518f), 4.4167f);
        up -= 4.0f * __expf(fmaf(109.451f, oy, -100.006f));
        float un = 0.063f + 0.8f * __expf(-75.0f * (ox + 0.001f));
        un = fmaf(-0.012f,  ftanh((ox - 0.127f) * 62.5f),        un);
        un = fmaf(-0.0118f, ftanh((ox - 0.155f) * 62.5f),        un);
        un = fmaf(-0.0035f, ftanh((ox - 0.22f)  * 50.0f),        un);
        un = fmaf(-0.0095f, ftanh((ox - 0.19f)  * 76.9230769f),  un);
        un = fmaf(-0.0145f, ftanh((ox - 0.49f)  * 50.0f),        un);
        un = fmaf(-0.08f,   ftanh((ox - 1.03f)  * 18.1818182f),  un);
        float OCV = up - un;

        if (j == 0) {
            float p2 = bb2[2];
            p2 = fmaf(h0, w2[0*7+2], p2); p2 = fmaf(h1, w2[1*7+2], p2);
            p2 = fmaf(h2, w2[2*7+2], p2); p2 = fmaf(h3, w2[3*7+2], p2);
            p2 = fmaf(h4, w2[4*7+2], p2); p2 = fmaf(h5, w2[5*7+2], p2);
            float OCVU = fmaf(0.75f, fsigm(0.01f * p2), 0.05f);
            U10_local = -OCVU - ii * R0;
        }

        // stash: pred[j] = P[j] + Apre[j]*U1_start   (UH == 0)
        ldsA[PADJ(j)] = fmaf(ii, R0, OCV) + Bp;
        ldsB[PADJ(j)] = Ap;

        // step j: U1' = (1 - dtI*C)*U1 + dtI*C*R1*I
        float g  = (inx - ii) * C;
        float aj = 1.0f - g;
        float bj = g * R1 * ii;
        if (j == TT - 1) { aj = 1.0f; bj = 0.0f; }
        Bp = fmaf(aj, Bp, bj);
        Ap = aj * Ap;
    }

    // ---- affine block scan (composition (a2,b2)∘(a1,b1) = (a2*a1, a2*b1+b2)) ----
    float A = Ap, B = Bp;
    #pragma unroll
    for (int d = 1; d < 64; d <<= 1) {
        float Au = __shfl_up(A, d, 64);
        float Bu = __shfl_up(B, d, 64);
        if (lane >= d) { B = fmaf(A, Bu, B); A = A * Au; }
    }
    float Aex = __shfl_up(A, 1, 64);
    float Bex = __shfl_up(B, 1, 64);
    if (lane == 0) { Aex = 1.0f; Bex = 0.0f; }
    if (lane == 63) { sA[wv] = A; sB[wv] = B; }
    if (tid == 0) bcU10 = U10_local;
    __syncthreads();                                    // S5
    float Ao = 1.0f, Bo = 0.0f;
    for (int w = 0; w < wv; ++w) {                      // wave-uniform, <=3 iters
        Bo = fmaf(sA[w], Bo, sB[w]);
        Ao = sA[w] * Ao;
    }
    const float U10 = bcU10;
    const float U1s = fmaf(Aex * Ao, U10, fmaf(Aex, Bo, Bex));
    U1arr[tid] = U1s;
    __syncthreads();                                    // S6

    // ---- Phase 3: coalesced output ----
    float* __restrict__ orow = out + (size_t)b * TT;
    #pragma unroll 4
    for (int it = 0; it < EPT; ++it) {
        int j = tid + it * BLK;
        float P    = ldsA[PADJ(j)];
        float Apre = ldsB[PADJ(j)];
        orow[j] = fmaf(Apre, U1arr[j >> 5], P);
    }
}

extern "C" void kernel_launch(void* const* d_in, const int* in_sizes, int n_in,
                              void* d_out, int out_size, void* d_ws, size_t ws_size,
                              hipStream_t stream)
{
    const float* X  = (const float*)d_in[0];
    const float* SC = (const float*)d_in[1];
    const float* W1 = (const float*)d_in[2];
    const float* b1 = (const float*)d_in[3];
    const float* W2 = (const float*)d_in[4];
    const float* b2 = (const float*)d_in[5];
    float* outp = (float*)d_out;
    const int B = in_sizes[1] / 2;   // SC is (B,2)
    hipLaunchKernelGGL(voltnet_kernel, dim3(B), dim3(BLK), 0, stream,
                       X, SC, W1, b1, W2, b2, outp);
}